// Round 8
// baseline (36.450 us; speedup 1.0000x reference)
//
#include <hip/hip_runtime.h>

typedef float f4 __attribute__((ext_vector_type(4)));
typedef float f4u __attribute__((ext_vector_type(4), aligned(4)));

struct M3 { float m[3][3]; };

#define ELEM(q, n) ((q)[(n) >> 2][(n) & 3])

__device__ __forceinline__ M3 matmul(const M3& A, const M3& B) {  // A @ B
  M3 C;
#pragma unroll
  for (int i = 0; i < 3; ++i)
#pragma unroll
    for (int j = 0; j < 3; ++j)
      C.m[i][j] = A.m[i][0]*B.m[0][j] + A.m[i][1]*B.m[1][j] + A.m[i][2]*B.m[2][j];
  return C;
}

// matrix k (0..7) of the 8-frame window held in 18 f4 regs; k compile-time
__device__ __forceinline__ M3 mk18(const f4 (&q)[18], int k) {
  M3 A;
#pragma unroll
  for (int i = 0; i < 3; ++i)
#pragma unroll
    for (int j = 0; j < 3; ++j)
      A.m[i][j] = ELEM(q, 9*k + 3*i + j);
  return A;
}

template <int CTRL>
__device__ __forceinline__ float dppf(float v) {
  return __int_as_float(
      __builtin_amdgcn_mov_dpp(__float_as_int(v), CTRL, 0xf, 0xf, true));
}

template <int D>  // row_shr:D (8-lane subgroups are 8-aligned; masked by s>=D)
__device__ __forceinline__ M3 dpp_shr_mat(const M3& A) {
  M3 C;
#pragma unroll
  for (int i = 0; i < 3; ++i)
#pragma unroll
    for (int j = 0; j < 3; ++j)
      C.m[i][j] = dppf<0x110 + D>(A.m[i][j]);
  return C;
}

__device__ __forceinline__ float sigm(float z) {
  return __builtin_amdgcn_rcpf(1.0f + __expf(-z));
}
__device__ __forceinline__ float tanh_(float z) {
  float e = __expf(2.0f * z);
  return 1.0f - 2.0f * __builtin_amdgcn_rcpf(e + 1.0f);
}

template <int CTRL>  // quad_perm broadcast within each 4-lane quad
__device__ __forceinline__ float quad_bcast(float v) {
  return __int_as_float(
      __builtin_amdgcn_mov_dpp(__float_as_int(v), CTRL, 0xf, 0xf, true));
}

// One wave (64 threads) per block; 8 elements/block, 8 lanes/element.
// Blocks [0, nbBack): back chains (rows 0..63) + LSTM (row 64).
// Blocks [nbBack, 2*nbBack): fwd chains (rows 65..127).
// Loads are COALESCED: wave loads its 8 half-regions contiguously, LDS-transposes,
// then each lane ds_reads its own 8-frame segment window.
__global__ __launch_bounds__(64, 2) void fused_kernel(
    const float* __restrict__ dir, const float* __restrict__ R,
    const float* __restrict__ Wih, const float* __restrict__ Whh,
    const float* __restrict__ bih, const float* __restrict__ bhh,
    float* __restrict__ out, int B, int nbBack) {
  __shared__ __align__(16) f4 lds[8 * 145];  // 18560 B; reused as xrows[64][9]

  const int lane = threadIdx.x;
  const int e = lane >> 3;
  const int s = lane & 7;
  const bool isBack = ((int)blockIdx.x < nbBack);
  const int blk = isBack ? (int)blockIdx.x : ((int)blockIdx.x - nbBack);
  const int b0 = blk * 8;
  const int b = b0 + e;
  const bool valid = (b < B);
  const int bc = valid ? b : (B - 1);
  const int halfOff = isBack ? 0 : 576;  // back: frames 0..63, fwd: 64..127

  // ---- coalesced staging: global -> regs -> LDS transpose ----
  {
    f4 tb[18];
#pragma unroll
    for (int k = 0; k < 18; ++k) {
      const int c = lane + 64 * k;      // 16B chunk index in wave region
      const int ec = c / 144;           // element within wave
      const int rc = c - ec * 144;      // chunk within element half (0..143)
      int be = b0 + ec; be = (be < B) ? be : (B - 1);
      tb[k] = *(const f4*)(R + (size_t)be * 1152 + halfOff + rc * 4);
    }
#pragma unroll
    for (int k = 0; k < 18; ++k) {
      const int c = lane + 64 * k;
      const int ec = c / 144;
      const int rc = c - ec * 144;
      lds[ec * 145 + rc] = tb[k];
    }
  }

  // ---- per-lane segment window: 18 consecutive f4 = frames lo..lo+7 ----
  f4 q[18];
  {
    const int off = e * 145 + (isBack ? (126 - 18 * s) : (18 * s));
#pragma unroll
    for (int i = 0; i < 18; ++i) q[i] = lds[off + i];
  }

  const float d0 = dir[3*bc+0], d1 = dir[3*bc+1], d2 = dir[3*bc+2];

  // ---- segment product P = A_{lo+7} @ ... @ A_{lo} (natural matrices) ----
  M3 P = mk18(q, 0);
#pragma unroll
  for (int k = 1; k < 8; ++k) P = matmul(mk18(q, k), P);

  // ---- 8-lane DPP scan ----
  M3 I = P;
  if (isBack) {
    // K-order scan (prev on LEFT): I_s = P_0 @ P_1 @ ... @ P_s
    {
      M3 Sh = dpp_shr_mat<1>(I); M3 T = matmul(Sh, I);
#pragma unroll
      for (int i = 0; i < 3; ++i)
#pragma unroll
        for (int j = 0; j < 3; ++j) I.m[i][j] = (s >= 1) ? T.m[i][j] : I.m[i][j];
    }
    {
      M3 Sh = dpp_shr_mat<2>(I); M3 T = matmul(Sh, I);
#pragma unroll
      for (int i = 0; i < 3; ++i)
#pragma unroll
        for (int j = 0; j < 3; ++j) I.m[i][j] = (s >= 2) ? T.m[i][j] : I.m[i][j];
    }
    {
      M3 Sh = dpp_shr_mat<4>(I); M3 T = matmul(Sh, I);
#pragma unroll
      for (int i = 0; i < 3; ++i)
#pragma unroll
        for (int j = 0; j < 3; ++j) I.m[i][j] = (s >= 4) ? T.m[i][j] : I.m[i][j];
    }
  } else {
    // fwd scan: I_s = S_s @ S_{s-1} @ ... @ S_0
    {
      M3 Sh = dpp_shr_mat<1>(I); M3 T = matmul(I, Sh);
#pragma unroll
      for (int i = 0; i < 3; ++i)
#pragma unroll
        for (int j = 0; j < 3; ++j) I.m[i][j] = (s >= 1) ? T.m[i][j] : I.m[i][j];
    }
    {
      M3 Sh = dpp_shr_mat<2>(I); M3 T = matmul(I, Sh);
#pragma unroll
      for (int i = 0; i < 3; ++i)
#pragma unroll
        for (int j = 0; j < 3; ++j) I.m[i][j] = (s >= 2) ? T.m[i][j] : I.m[i][j];
    }
    {
      M3 Sh = dpp_shr_mat<4>(I); M3 T = matmul(I, Sh);
#pragma unroll
      for (int i = 0; i < 3; ++i)
#pragma unroll
        for (int j = 0; j < 3; ++j) I.m[i][j] = (s >= 4) ? T.m[i][j] : I.m[i][j];
    }
  }

  // w = chain state after this segment's last row
  float w0, w1, w2;
  if (isBack) {  // w = I^T @ d
    w0 = I.m[0][0]*d0 + I.m[1][0]*d1 + I.m[2][0]*d2;
    w1 = I.m[0][1]*d0 + I.m[1][1]*d1 + I.m[2][1]*d2;
    w2 = I.m[0][2]*d0 + I.m[1][2]*d1 + I.m[2][2]*d2;
  } else {       // w = I @ d
    w0 = I.m[0][0]*d0 + I.m[0][1]*d1 + I.m[0][2]*d2;
    w1 = I.m[1][0]*d0 + I.m[1][1]*d1 + I.m[1][2]*d2;
    w2 = I.m[2][0]*d0 + I.m[2][1]*d1 + I.m[2][2]*d2;
  }
  float p0 = dppf<0x111>(w0), p1 = dppf<0x111>(w1), p2 = dppf<0x111>(w2);
  float v0 = (s == 0) ? d0 : p0;
  float v1 = (s == 0) ? d1 : p1;
  float v2 = (s == 0) ? d2 : p2;

  // ---- rows ----
  float row[24];
  if (isBack) {  // r_j = A_{lo+7-j}^T @ r_{j-1}, row-vector form
#pragma unroll
    for (int j = 0; j < 8; ++j) {
      M3 A = mk18(q, 7 - j);
      float n0 = v0*A.m[0][0] + v1*A.m[1][0] + v2*A.m[2][0];
      float n1 = v0*A.m[0][1] + v1*A.m[1][1] + v2*A.m[2][1];
      float n2 = v0*A.m[0][2] + v1*A.m[1][2] + v2*A.m[2][2];
      v0 = n0; v1 = n1; v2 = n2;
      row[3*j+0] = n0; row[3*j+1] = n1; row[3*j+2] = n2;
    }
  } else {       // r_j = A_{lo+j} @ r_{j-1}
#pragma unroll
    for (int j = 0; j < 8; ++j) {
      M3 A = mk18(q, j);
      float n0 = A.m[0][0]*v0 + A.m[0][1]*v1 + A.m[0][2]*v2;
      float n1 = A.m[1][0]*v0 + A.m[1][1]*v1 + A.m[1][2]*v2;
      float n2 = A.m[2][0]*v0 + A.m[2][1]*v1 + A.m[2][2]*v2;
      v0 = n0; v1 = n1; v2 = n2;
      row[3*j+0] = n0; row[3*j+1] = n1; row[3*j+2] = n2;
    }
  }

  if (!isBack) {
    if (valid) {  // rows 65+8s .. (s=7: only 7 rows)
      float* ob = out + (size_t)b * 384 + (size_t)(65 + 8*s) * 3;
#pragma unroll
      for (int kk = 0; kk < 5; ++kk) {
        f4u vv = { row[4*kk+0], row[4*kk+1], row[4*kk+2], row[4*kk+3] };
        *(f4u*)(ob + 4*kk) = vv;
      }
      ob[20] = row[20];
      if (s < 7) { ob[21] = row[21]; ob[22] = row[22]; ob[23] = row[23]; }
    }
    return;
  }

  // ======================= back-only epilogue =======================
  if (valid) {  // rows 8s..8s+7: 24 floats, 16B-aligned
    float* ob = out + (size_t)b * 384 + 24 * s;
#pragma unroll
    for (int kk = 0; kk < 6; ++kk) {
      f4 vv = { row[4*kk+0], row[4*kk+1], row[4*kk+2], row[4*kk+3] };
      ((f4*)ob)[kk] = vv;
    }
  }

  // deposit x rows into LDS (reusing staging buffer; q already consumed)
#pragma unroll
  for (int j = 0; j < 8; ++j) {
    f4 vv = { row[3*j+0], row[3*j+1], row[3*j+2], 0.f };
    lds[(8*s + j) * 9 + e] = vv;
  }

  // ---- LSTM: 8 elements x 4 lanes (unit per lane), quad DPP broadcast ----
  if (lane >= 32) return;
  const int e2 = lane >> 2;
  const int u = lane & 3, uu = (u == 3) ? 0 : u;
  const int b2 = b0 + e2;
  const bool valid2 = (b2 < B);
  const int b2c = valid2 ? b2 : 0;

  const float wii0 = Wih[uu*3+0],     wii1 = Wih[uu*3+1],     wii2 = Wih[uu*3+2];
  const float wif0 = Wih[(3+uu)*3+0], wif1 = Wih[(3+uu)*3+1], wif2 = Wih[(3+uu)*3+2];
  const float wig0 = Wih[(6+uu)*3+0], wig1 = Wih[(6+uu)*3+1], wig2 = Wih[(6+uu)*3+2];
  const float wio0 = Wih[(9+uu)*3+0], wio1 = Wih[(9+uu)*3+1], wio2 = Wih[(9+uu)*3+2];
  const float whi0 = Whh[uu*3+0],     whi1 = Whh[uu*3+1],     whi2 = Whh[uu*3+2];
  const float whf0 = Whh[(3+uu)*3+0], whf1 = Whh[(3+uu)*3+1], whf2 = Whh[(3+uu)*3+2];
  const float whg0 = Whh[(6+uu)*3+0], whg1 = Whh[(6+uu)*3+1], whg2 = Whh[(6+uu)*3+2];
  const float who0 = Whh[(9+uu)*3+0], who1 = Whh[(9+uu)*3+1], who2 = Whh[(9+uu)*3+2];
  const float bsi = bih[uu]   + bhh[uu];
  const float bsf = bih[3+uu] + bhh[3+uu];
  const float bsg = bih[6+uu] + bhh[6+uu];
  const float bso = bih[9+uu] + bhh[9+uu];
  const float dd0 = dir[3*b2c+0], dd1 = dir[3*b2c+1], dd2 = dir[3*b2c+2];

  float h0 = 0.f, h1 = 0.f, h2 = 0.f, cc = 0.f, hl = 0.f;

#define LSTEP(x0_, x1_, x2_)                                                  \
  {                                                                           \
    float zi = bsi + wii0*(x0_) + wii1*(x1_) + wii2*(x2_)                     \
                   + whi0*h0 + whi1*h1 + whi2*h2;                             \
    float zf = bsf + wif0*(x0_) + wif1*(x1_) + wif2*(x2_)                     \
                   + whf0*h0 + whf1*h1 + whf2*h2;                             \
    float zg = bsg + wig0*(x0_) + wig1*(x1_) + wig2*(x2_)                     \
                   + whg0*h0 + whg1*h1 + whg2*h2;                             \
    float zo = bso + wio0*(x0_) + wio1*(x1_) + wio2*(x2_)                     \
                   + who0*h0 + who1*h1 + who2*h2;                             \
    float ai = sigm(zi), af = sigm(zf), ag = tanh_(zg), ao = sigm(zo);        \
    cc = af*cc + ai*ag;                                                       \
    float hn = ao * tanh_(cc);                                                \
    hl = hn;                                                                  \
    h0 = quad_bcast<0x00>(hn);                                                \
    h1 = quad_bcast<0x55>(hn);                                                \
    h2 = quad_bcast<0xAA>(hn);                                                \
  }

  f4 xa[8], xb[8];
#pragma unroll
  for (int j = 0; j < 8; ++j) xa[j] = lds[j * 9 + e2];
#pragma unroll
  for (int c = 0; c < 8; ++c) {
    if (c < 7) {
      if ((c & 1) == 0) {
#pragma unroll
        for (int j = 0; j < 8; ++j) xb[j] = lds[((c+1)*8 + j) * 9 + e2];
      } else {
#pragma unroll
        for (int j = 0; j < 8; ++j) xa[j] = lds[((c+1)*8 + j) * 9 + e2];
      }
    }
#pragma unroll
    for (int j = 0; j < 8; ++j) {
      f4 x = ((c & 1) == 0) ? xa[j] : xb[j];
      LSTEP(x[0], x[1], x[2]);
    }
  }
  LSTEP(dd0, dd1, dd2);  // final step t=64 with x = dir
#undef LSTEP

  if (valid2 && u < 3) out[(size_t)b2 * 384 + 192 + u] = hl;
}

extern "C" void kernel_launch(void* const* d_in, const int* in_sizes, int n_in,
                              void* d_out, int out_size, void* d_ws, size_t ws_size,
                              hipStream_t stream) {
  const float* dir = (const float*)d_in[0];
  const float* R   = (const float*)d_in[1];
  const float* Wih = (const float*)d_in[2];
  const float* Whh = (const float*)d_in[3];
  const float* bih = (const float*)d_in[4];
  const float* bhh = (const float*)d_in[5];
  float* out = (float*)d_out;

  const int B = in_sizes[0] / 3;     // 16384
  const int nbBack = (B + 7) / 8;    // 2048
  const int grid = nbBack * 2;       // back blocks then fwd blocks
  hipLaunchKernelGGL(fused_kernel, dim3(grid), dim3(64), 0, stream,
                     dir, R, Wih, Whh, bih, bhh, out, B, nbBack);
}